// Round 3
// baseline (208.778 us; speedup 1.0000x reference)
//
#include <hip/hip_runtime.h>
#include <math.h>

// Problem constants (fixed by reference setup_inputs)
constexpr int CIN  = 256;
constexpr int NST  = 512;          // N
constexpr int LSEQ = 4096;
constexpr int BB   = 4;
constexpr int ROWS = BB * LSEQ;    // 16384
constexpr int COUT = 256;
constexpr int LC   = 64;           // scan chunk length == proj row-tile
constexpr int NC   = LSEQ / LC;    // 64 chunks per batch

typedef __attribute__((ext_vector_type(8))) short bf16x8;
typedef __attribute__((ext_vector_type(4))) float f32x4;
typedef unsigned short ushort_t;
typedef unsigned int   uint_t;

__device__ __forceinline__ ushort_t f2bf(float f) {
    uint_t u = __float_as_uint(f);
    u = (u + 0x7FFF + ((u >> 16) & 1)) >> 16;   // RNE
    return (ushort_t)u;
}
__device__ __forceinline__ float bf2f(ushort_t s) {
    return __uint_as_float(((uint_t)s) << 16);
}

// ---------------------------------------------------------------------------
// prep: merged weight conversion (transposed to [n][k], bf16) + x -> bf16.
//   gid < 1048576           : x quad (4 elems)
//   next 524288             : Wt elem  (4 mats: Wx, Wbc lo, Wbc hi, Wd)
//   next 131072             : Wyt elem
// ---------------------------------------------------------------------------
__global__ __launch_bounds__(256)
void prep_kernel(const float* __restrict__ x,
                 const float* __restrict__ Wx, const float* __restrict__ Wbc,
                 const float* __restrict__ Wd, const float* __restrict__ Wy,
                 ushort_t* __restrict__ xb, ushort_t* __restrict__ Wt,
                 ushort_t* __restrict__ Wyt)
{
    const int gid = blockIdx.x * 256 + threadIdx.x;
    if (gid < ROWS * CIN / 4) {
        const int i = gid * 4;
        float4 v = *(const float4*)&x[i];
        uint2 o;
        o.x = (uint_t)f2bf(v.x) | ((uint_t)f2bf(v.y) << 16);
        o.y = (uint_t)f2bf(v.z) | ((uint_t)f2bf(v.w) << 16);
        *(uint2*)&xb[i] = o;
    } else if (gid < ROWS * CIN / 4 + 4 * NST * CIN) {
        const int wid = gid - ROWS * CIN / 4;
        const int mat = wid >> 17;            // 512*256 = 131072 per mat
        const int idx = wid & 131071;
        const int k   = idx >> 9;             // 0..255
        const int n   = idx & 511;            // 0..511 (coalesced reads)
        float v;
        if      (mat == 0) v = Wx [k * NST + n];
        else if (mat == 1) v = Wbc[k * (2 * NST) + n];
        else if (mat == 2) v = Wbc[k * (2 * NST) + NST + n];
        else               v = Wd [k * NST + n];
        Wt[((size_t)mat * NST + n) * CIN + k] = f2bf(v);
    } else {
        const int idx = gid - (ROWS * CIN / 4 + 4 * NST * CIN);
        const int k   = idx >> 8;             // 0..511
        const int n   = idx & 255;            // 0..255
        Wyt[(size_t)n * NST + k] = f2bf(Wy[k * COUT + n]);
    }
}

// ---------------------------------------------------------------------------
// proj_scan: fused 4-matrix projection MFMA GEMM + elementwise epilogue +
// in-block chunk-local scan (the 64-row tile IS one scan chunk).
//
// Outputs per element (t=local row, n): packed uint32
//     lo16 = bf16(C * hloc)   hi16 = bf16(C * Apre)
// where hloc = local scan of h with h_in=0, Apre = prefix prod of A.
// Plus per (chunk, n): Aprod (= full-chunk prod A), Hend (= hloc at t=63).
//
// Final combine (in out_fused): y(t,n) = G1 + G2 * carry(chunk, n).
//
// Scan is 2-level inside the block: 4 segments of 16 t (wave w = segment w,
// lane j = local n), fp32 throughout, via LDS overlay of the GEMM tiles.
// ---------------------------------------------------------------------------
__global__ __launch_bounds__(256, 3)
void proj_scan_kernel(const ushort_t* __restrict__ xb, const ushort_t* __restrict__ Wt,
                      const float* __restrict__ bx, const float* __restrict__ bbc,
                      const float* __restrict__ bd,
                      uint_t* __restrict__ HP,
                      float* __restrict__ Aprod, float* __restrict__ Hend)
{
    __shared__ union {
        struct {
            ushort_t xs[64][72];
            ushort_t ws[4][64][72];
        } g;                                       // 46080 B (GEMM phase)
        struct {
            float    Als[64][68];                  // A, then prefix-prod
            float    Uls[64][68];                  // u, then hloc / packed out
            ushort_t Cls[64][72];                  // C (bf16)
            float    Pseg[4][64];
            float    Hseg[4][64];
            float    Cp[4][64];
            float    Ch[4][64];
        } s;                                       // 48128 B (scan phase)
    } sh;

    const int tid  = threadIdx.x;
    const int wave = tid >> 6;
    const int lane = tid & 63;
    const int lm   = lane & 15;       // 16-dim index (row for A, n for B/D)
    const int lq   = lane >> 4;       // k-quad / row-quad
    const int row0 = blockIdx.x * 64; // == chunk * LC
    const int n0   = blockIdx.y * 64;

    const int sr = tid >> 2;          // staging row / n
    const int sk = (tid & 3) << 4;    // staging k offset (16 elems)

    f32x4 acc[4][4];                  // [rowtile][mat]
    #pragma unroll
    for (int rt = 0; rt < 4; ++rt)
        #pragma unroll
        for (int m = 0; m < 4; ++m)
            acc[rt][m] = (f32x4){0.f, 0.f, 0.f, 0.f};

    const ushort_t* xsrc  = xb + (size_t)(row0 + sr) * CIN + sk;
    const ushort_t* wsrc0 = Wt + (size_t)(n0 + sr) * CIN + sk;

    for (int k0 = 0; k0 < CIN; k0 += 64) {
        uint4 xv0 = *(const uint4*)(xsrc + k0);
        uint4 xv1 = *(const uint4*)(xsrc + k0 + 8);
        uint4 wv[4][2];
        #pragma unroll
        for (int m = 0; m < 4; ++m) {
            const ushort_t* p = wsrc0 + (size_t)m * NST * CIN + k0;
            wv[m][0] = *(const uint4*)(p);
            wv[m][1] = *(const uint4*)(p + 8);
        }
        __syncthreads();
        *(uint4*)&sh.g.xs[sr][sk]     = xv0;
        *(uint4*)&sh.g.xs[sr][sk + 8] = xv1;
        #pragma unroll
        for (int m = 0; m < 4; ++m) {
            *(uint4*)&sh.g.ws[m][sr][sk]     = wv[m][0];
            *(uint4*)&sh.g.ws[m][sr][sk + 8] = wv[m][1];
        }
        __syncthreads();

        #pragma unroll
        for (int ks = 0; ks < 2; ++ks) {
            const int kk = ks * 32 + lq * 8;
            bf16x8 af[4], bfr[4];
            #pragma unroll
            for (int rt = 0; rt < 4; ++rt)
                af[rt] = *(const bf16x8*)&sh.g.xs[rt * 16 + lm][kk];
            #pragma unroll
            for (int m = 0; m < 4; ++m)
                bfr[m] = *(const bf16x8*)&sh.g.ws[m][wave * 16 + lm][kk];
            #pragma unroll
            for (int rt = 0; rt < 4; ++rt)
                #pragma unroll
                for (int m = 0; m < 4; ++m)
                    acc[rt][m] = __builtin_amdgcn_mfma_f32_16x16x32_bf16(
                        af[rt], bfr[m], acc[rt][m], 0, 0, 0);
        }
    }

    __syncthreads();   // all GEMM-phase LDS reads done before overlay reuse

    // ---- E1: elementwise epilogue -> LDS [t][n_local] ----
    const int jn = wave * 16 + lm;     // n local
    const int ng = n0 + jn;
    const float bxv = bx [ng];
    const float bbv = bbc[ng];
    const float bcv = bbc[NST + ng];
    const float bdv = bd [ng];
    #pragma unroll
    for (int rt = 0; rt < 4; ++rt) {
        #pragma unroll
        for (int r = 0; r < 4; ++r) {
            const int t = rt * 16 + lq * 4 + r;
            float xp = acc[rt][0][r] + bxv;
            float bm = acc[rt][1][r] + bbv;
            float cc = acc[rt][2][r] + bcv;
            float dd = acc[rt][3][r] + bdv;
            dd = fminf(dd, 60.0f);
            float e  = __expf(dd);
            float A  = 1.0f / (1.0f + e);        // exp(-softplus(d))
            float u  = (e * A) * bm * xp;        // (1-A)*Bm*x_proj
            sh.s.Als[t][jn] = A;
            sh.s.Uls[t][jn] = u;
            sh.s.Cls[t][jn] = f2bf(cc);
        }
    }
    __syncthreads();

    // ---- Pass A: per-segment scan (wave w = segment w, lane = n local) ----
    {
        const int j = lane, w = wave;
        float p = 1.0f, h = 0.0f;
        #pragma unroll
        for (int i = 0; i < 16; ++i) {
            const int t = w * 16 + i;
            float a  = sh.s.Als[t][j];
            float uu = sh.s.Uls[t][j];
            h = fmaf(a, h, uu);
            p *= a;
            sh.s.Als[t][j] = p;     // segment-local prefix prod
            sh.s.Uls[t][j] = h;     // segment-local h
        }
        sh.s.Pseg[w][j] = p;
        sh.s.Hseg[w][j] = h;
    }
    __syncthreads();

    // ---- combine across 4 segments (one wave) + chunk summary ----
    if (tid < 64) {
        const int j = tid;
        float cp = 1.0f, ch = 0.0f;
        #pragma unroll
        for (int s = 0; s < 4; ++s) {
            sh.s.Cp[s][j] = cp;
            sh.s.Ch[s][j] = ch;
            float ps = sh.s.Pseg[s][j];
            float hs = sh.s.Hseg[s][j];
            ch = fmaf(ps, ch, hs);
            cp *= ps;
        }
        Aprod[(size_t)blockIdx.x * NST + n0 + j] = cp;
        Hend [(size_t)blockIdx.x * NST + n0 + j] = ch;
    }
    __syncthreads();

    // ---- Pass B: apply segment carry, premultiply by C, pack bf16x2 ----
    {
        const int j = lane, w = wave;
        const float cpw = sh.s.Cp[w][j];
        const float chw = sh.s.Ch[w][j];
        #pragma unroll
        for (int i = 0; i < 16; ++i) {
            const int t = w * 16 + i;
            float p = sh.s.Als[t][j];
            float h = sh.s.Uls[t][j];
            float c = bf2f(sh.s.Cls[t][j]);
            float hf = fmaf(p, chw, h);          // hloc (chunk-local)
            float pf = p * cpw;                  // Apre (chunk-local)
            uint_t g1 = f2bf(c * hf);
            uint_t g2 = f2bf(c * pf);
            ((uint_t*)&sh.s.Uls[t][0])[j] = (g2 << 16) | g1;
        }
    }
    __syncthreads();

    // ---- store packed HP, vectorized ----
    {
        const int r  = tid >> 2;
        const int nq = (tid & 3) * 16;
        const uint_t* src = (const uint_t*)&sh.s.Uls[r][0] + nq;
        uint_t* dst = HP + (size_t)(row0 + r) * NST + n0 + nq;
        uint4 v0 = *(const uint4*)(src);
        uint4 v1 = *(const uint4*)(src + 4);
        uint4 v2 = *(const uint4*)(src + 8);
        uint4 v3 = *(const uint4*)(src + 12);
        *(uint4*)(dst)      = v0;
        *(uint4*)(dst + 4)  = v1;
        *(uint4*)(dst + 8)  = v2;
        *(uint4*)(dst + 12) = v3;
    }
}

// ---------------------------------------------------------------------------
// carry: per (b, n) sequential scan over the 64 chunk summaries.
// Carry[b, c, n] = h entering chunk c.
// ---------------------------------------------------------------------------
__global__ __launch_bounds__(256)
void scan_carry_kernel(const float* __restrict__ Aprod, const float* __restrict__ Hend,
                       float* __restrict__ Carry)
{
    const int gid = blockIdx.x * 256 + threadIdx.x;   // 0 .. BB*NST-1
    const int n   = gid & (NST - 1);
    const int b   = gid >> 9;
    float h = 0.0f;
    for (int c = 0; c < NC; ++c) {
        size_t idx = ((size_t)(b * NC + c)) * NST + n;
        Carry[idx] = h;
        h = fmaf(Aprod[idx], h, Hend[idx]);
    }
}

// ---------------------------------------------------------------------------
// out_fused: out = y @ Wy + by where y(t,n) = G1 + G2*carry(chunk,n) is
// reconstructed from packed HP during LDS staging. Tile 64 rows x 64 cols.
// Row block == one chunk, so carry row is wave-uniform per block.
// ---------------------------------------------------------------------------
__global__ __launch_bounds__(256, 4)
void out_fused_kernel(const uint_t* __restrict__ HP, const float* __restrict__ Carry,
                      const ushort_t* __restrict__ Wyt, const float* __restrict__ by,
                      float* __restrict__ out)
{
    __shared__ alignas(16) ushort_t ys [64][72];
    __shared__ alignas(16) ushort_t wys[64][72];

    const int tid  = threadIdx.x;
    const int wave = tid >> 6;
    const int lane = tid & 63;
    const int lm   = lane & 15;
    const int lq   = lane >> 4;
    const int row0 = blockIdx.x * 64;     // == chunk * LC
    const int n0   = blockIdx.y * 64;

    const int sr = tid >> 2;
    const int sk = (tid & 3) << 4;

    f32x4 acc[4];
    #pragma unroll
    for (int rt = 0; rt < 4; ++rt) acc[rt] = (f32x4){0.f, 0.f, 0.f, 0.f};

    const uint_t*   hsrc = HP  + (size_t)(row0 + sr) * NST + sk;
    const ushort_t* wsrc = Wyt + (size_t)(n0  + sr) * NST + sk;
    const float*    carr = Carry + (size_t)blockIdx.x * NST + sk;

    for (int k0 = 0; k0 < NST; k0 += 64) {
        uint4 hv[4];
        #pragma unroll
        for (int q = 0; q < 4; ++q) hv[q] = *(const uint4*)(hsrc + k0 + q * 4);
        float4 cv[4];
        #pragma unroll
        for (int q = 0; q < 4; ++q) cv[q] = *(const float4*)(carr + k0 + q * 4);
        uint4 wv0 = *(const uint4*)(wsrc + k0);
        uint4 wv1 = *(const uint4*)(wsrc + k0 + 8);

        // y = G1 + G2*carry -> bf16, pack 16 elems
        uint_t yo[8];
        #pragma unroll
        for (int q = 0; q < 4; ++q) {
            const float* cvp = (const float*)&cv[q];
            const uint_t* hvp = (const uint_t*)&hv[q];
            #pragma unroll
            for (int e = 0; e < 4; e += 2) {
                uint_t pk0 = hvp[e], pk1 = hvp[e + 1];
                float y0 = fmaf(bf2f((ushort_t)(pk0 >> 16)), cvp[e],
                                bf2f((ushort_t)(pk0 & 0xffff)));
                float y1 = fmaf(bf2f((ushort_t)(pk1 >> 16)), cvp[e + 1],
                                bf2f((ushort_t)(pk1 & 0xffff)));
                yo[q * 2 + e / 2] = (uint_t)f2bf(y0) | ((uint_t)f2bf(y1) << 16);
            }
        }
        __syncthreads();
        *(uint4*)&ys[sr][sk]      = *(uint4*)&yo[0];
        *(uint4*)&ys[sr][sk + 8]  = *(uint4*)&yo[4];
        *(uint4*)&wys[sr][sk]     = wv0;
        *(uint4*)&wys[sr][sk + 8] = wv1;
        __syncthreads();

        #pragma unroll
        for (int ks = 0; ks < 2; ++ks) {
            const int kk = ks * 32 + lq * 8;
            bf16x8 bfr = *(const bf16x8*)&wys[wave * 16 + lm][kk];
            #pragma unroll
            for (int rt = 0; rt < 4; ++rt) {
                bf16x8 af = *(const bf16x8*)&ys[rt * 16 + lm][kk];
                acc[rt] = __builtin_amdgcn_mfma_f32_16x16x32_bf16(
                    af, bfr, acc[rt], 0, 0, 0);
            }
        }
    }

    const int ng = n0 + wave * 16 + lm;
    const float bv = by[ng];
    #pragma unroll
    for (int rt = 0; rt < 4; ++rt)
        #pragma unroll
        for (int r = 0; r < 4; ++r) {
            const int row = row0 + rt * 16 + lq * 4 + r;
            out[(size_t)row * COUT + ng] = acc[rt][r] + bv;
        }
}

// ---------------------------------------------------------------------------
// Workspace layout (bytes, 16B aligned):
//   HP    uint32 ROWS*NST    33,554,432   (packed bf16 G1|G2)
//   xb    bf16   ROWS*CIN     8,388,608
//   Wt    bf16   4*NST*CIN    1,048,576
//   Wyt   bf16   COUT*NST       262,144
//   Aprod fp32   BB*NC*NST      524,288
//   Hend  fp32   BB*NC*NST      524,288
//   Carry fp32   BB*NC*NST      524,288
// total 44,826,624 B (well under the ~102 MB proven available)
// ---------------------------------------------------------------------------
extern "C" void kernel_launch(void* const* d_in, const int* in_sizes, int n_in,
                              void* d_out, int out_size, void* d_ws, size_t ws_size,
                              hipStream_t stream)
{
    const float* x   = (const float*)d_in[0];
    const float* Wx  = (const float*)d_in[1];
    const float* bx  = (const float*)d_in[2];
    const float* Wbc = (const float*)d_in[3];
    const float* bbc = (const float*)d_in[4];
    const float* Wd  = (const float*)d_in[5];
    const float* bd  = (const float*)d_in[6];
    const float* Wy  = (const float*)d_in[7];
    const float* by  = (const float*)d_in[8];
    float* out = (float*)d_out;

    char* p = (char*)d_ws;
    uint_t*   HP    = (uint_t*)p;         p += (size_t)ROWS * NST * 4;
    ushort_t* xb    = (ushort_t*)p;       p += (size_t)ROWS * CIN * 2;
    ushort_t* Wt    = (ushort_t*)p;       p += (size_t)4 * NST * CIN * 2;
    ushort_t* Wyt   = (ushort_t*)p;       p += (size_t)COUT * NST * 2;
    float*    Aprod = (float*)p;          p += (size_t)BB * NC * NST * 4;
    float*    Hend  = (float*)p;          p += (size_t)BB * NC * NST * 4;
    float*    Carry = (float*)p;          p += (size_t)BB * NC * NST * 4;

    const int prep_threads = ROWS * CIN / 4 + 4 * NST * CIN + COUT * NST;
    prep_kernel<<<prep_threads / 256, 256, 0, stream>>>(
        x, Wx, Wbc, Wd, Wy, xb, Wt, Wyt);

    proj_scan_kernel<<<dim3(ROWS / 64, NST / 64), 256, 0, stream>>>(
        xb, Wt, bx, bbc, bd, HP, Aprod, Hend);

    scan_carry_kernel<<<(BB * NST) / 256, 256, 0, stream>>>(
        Aprod, Hend, Carry);

    out_fused_kernel<<<dim3(ROWS / 64, COUT / 64), 256, 0, stream>>>(
        HP, Carry, Wyt, by, out);
}

// Round 4
// 204.765 us; speedup vs baseline: 1.0196x; 1.0196x over previous
//
#include <hip/hip_runtime.h>
#include <math.h>

// Problem constants (fixed by reference setup_inputs)
constexpr int CIN  = 256;
constexpr int NST  = 512;          // N
constexpr int LSEQ = 4096;
constexpr int BB   = 4;
constexpr int ROWS = BB * LSEQ;    // 16384
constexpr int COUT = 256;
constexpr int LC   = 64;           // scan chunk length == proj row-tile
constexpr int NC   = LSEQ / LC;    // 64 chunks per batch

typedef __attribute__((ext_vector_type(8))) short bf16x8;
typedef __attribute__((ext_vector_type(4))) float f32x4;
typedef unsigned short ushort_t;
typedef unsigned int   uint_t;

__device__ __forceinline__ ushort_t f2bf(float f) {
    uint_t u = __float_as_uint(f);
    u = (u + 0x7FFF + ((u >> 16) & 1)) >> 16;   // RNE
    return (ushort_t)u;
}
__device__ __forceinline__ float bf2f(ushort_t s) {
    return __uint_as_float(((uint_t)s) << 16);
}

// ---------------------------------------------------------------------------
// prep: merged weight conversion (transposed to [n][k], bf16) + x -> bf16.
// ---------------------------------------------------------------------------
__global__ __launch_bounds__(256)
void prep_kernel(const float* __restrict__ x,
                 const float* __restrict__ Wx, const float* __restrict__ Wbc,
                 const float* __restrict__ Wd, const float* __restrict__ Wy,
                 ushort_t* __restrict__ xb, ushort_t* __restrict__ Wt,
                 ushort_t* __restrict__ Wyt)
{
    const int gid = blockIdx.x * 256 + threadIdx.x;
    if (gid < ROWS * CIN / 4) {
        const int i = gid * 4;
        float4 v = *(const float4*)&x[i];
        uint2 o;
        o.x = (uint_t)f2bf(v.x) | ((uint_t)f2bf(v.y) << 16);
        o.y = (uint_t)f2bf(v.z) | ((uint_t)f2bf(v.w) << 16);
        *(uint2*)&xb[i] = o;
    } else if (gid < ROWS * CIN / 4 + 4 * NST * CIN) {
        const int wid = gid - ROWS * CIN / 4;
        const int mat = wid >> 17;            // 512*256 = 131072 per mat
        const int idx = wid & 131071;
        const int k   = idx >> 9;             // 0..255
        const int n   = idx & 511;            // 0..511 (coalesced reads)
        float v;
        if      (mat == 0) v = Wx [k * NST + n];
        else if (mat == 1) v = Wbc[k * (2 * NST) + n];
        else if (mat == 2) v = Wbc[k * (2 * NST) + NST + n];
        else               v = Wd [k * NST + n];
        Wt[((size_t)mat * NST + n) * CIN + k] = f2bf(v);
    } else {
        const int idx = gid - (ROWS * CIN / 4 + 4 * NST * CIN);
        const int k   = idx >> 8;             // 0..511
        const int n   = idx & 255;            // 0..255
        Wyt[(size_t)n * NST + k] = f2bf(Wy[k * COUT + n]);
    }
}

// ---------------------------------------------------------------------------
// proj_mfma_scan: round-2 GEMM structure (4-matrix MFMA, regular staging,
// padded LDS) + register/shuffle full chunk prefix in the epilogue.
//
// Output per element: HP packed uint32 {hi=bf16(C*Apre), lo=bf16(C*hloc)}
// where hloc = chunk-local scan value, Apre = prefix prod of A (incl t).
// Per (chunk, n): Aprod, Hend chunk summaries.
//
// Scan decomposition (t = rt*16 + lq*4 + r, n = wave*16 + lm, lane=lq*16+lm):
//   1. in-lane sequential prefix over r (4 runs of 4, one per rt)
//   2. cross-lq inclusive scan of run totals via __shfl_up(16), __shfl_up(32)
//      (+ shfl_up(16) for exclusive, + __shfl(48+lm) broadcast of block16 tot)
//   3. in-lane sequential compose across rt
// Pair compose (c1 then c2): (P,H) -> (P1*P2, P2*H1 + H2);  h_out = P*h_in + H.
// ---------------------------------------------------------------------------
__global__ __launch_bounds__(256, 3)
void proj_mfma_scan_kernel(const ushort_t* __restrict__ xb, const ushort_t* __restrict__ Wt,
                           const float* __restrict__ bx, const float* __restrict__ bbc,
                           const float* __restrict__ bd,
                           uint_t* __restrict__ HP,
                           float* __restrict__ Aprod, float* __restrict__ Hend)
{
    __shared__ union {
        struct {
            ushort_t xs[64][72];
            ushort_t ws[4][64][72];
        } g;                                   // 46080 B (GEMM phase)
        struct {
            uint_t po[64][68];                 // 17408 B (store transpose)
        } s;
    } sh;

    const int tid  = threadIdx.x;
    const int wave = tid >> 6;
    const int lane = tid & 63;
    const int lm   = lane & 15;       // n within wave-slice / MFMA col
    const int lq   = lane >> 4;       // row-quad within block16
    const int row0 = blockIdx.x * 64; // == chunk * LC
    const int n0   = blockIdx.y * 64;

    const int sr = tid >> 2;          // staging row / n
    const int sk = (tid & 3) << 4;    // staging k offset (16 ushorts)

    f32x4 acc[4][4];                  // [rowtile][mat]
    #pragma unroll
    for (int rt = 0; rt < 4; ++rt)
        #pragma unroll
        for (int m = 0; m < 4; ++m)
            acc[rt][m] = (f32x4){0.f, 0.f, 0.f, 0.f};

    const ushort_t* xsrc  = xb + (size_t)(row0 + sr) * CIN + sk;
    const ushort_t* wsrc0 = Wt + (size_t)(n0 + sr) * CIN + sk;

    for (int k0 = 0; k0 < CIN; k0 += 64) {
        uint4 xv0 = *(const uint4*)(xsrc + k0);
        uint4 xv1 = *(const uint4*)(xsrc + k0 + 8);
        uint4 wv[4][2];
        #pragma unroll
        for (int m = 0; m < 4; ++m) {
            const ushort_t* p = wsrc0 + (size_t)m * NST * CIN + k0;
            wv[m][0] = *(const uint4*)(p);
            wv[m][1] = *(const uint4*)(p + 8);
        }
        __syncthreads();   // previous iteration's LDS reads must finish
        *(uint4*)&sh.g.xs[sr][sk]     = xv0;
        *(uint4*)&sh.g.xs[sr][sk + 8] = xv1;
        #pragma unroll
        for (int m = 0; m < 4; ++m) {
            *(uint4*)&sh.g.ws[m][sr][sk]     = wv[m][0];
            *(uint4*)&sh.g.ws[m][sr][sk + 8] = wv[m][1];
        }
        __syncthreads();

        #pragma unroll
        for (int ks = 0; ks < 2; ++ks) {
            const int kk = ks * 32 + lq * 8;
            bf16x8 af[4], bfr[4];
            #pragma unroll
            for (int rt = 0; rt < 4; ++rt)
                af[rt] = *(const bf16x8*)&sh.g.xs[rt * 16 + lm][kk];
            #pragma unroll
            for (int m = 0; m < 4; ++m)
                bfr[m] = *(const bf16x8*)&sh.g.ws[m][wave * 16 + lm][kk];
            #pragma unroll
            for (int rt = 0; rt < 4; ++rt)
                #pragma unroll
                for (int m = 0; m < 4; ++m)
                    acc[rt][m] = __builtin_amdgcn_mfma_f32_16x16x32_bf16(
                        af[rt], bfr[m], acc[rt][m], 0, 0, 0);
        }
    }

    // ===== epilogue: elementwise + in-register chunk scan =====
    const int jn = wave * 16 + lm;     // n local (0..63)
    const int ng = n0 + jn;
    const float bxv = bx [ng];
    const float bbv = bbc[ng];
    const float bcv = bbc[NST + ng];
    const float bdv = bd [ng];

    // step 1: per-run (rt) in-lane prefix over the 4 consecutive t
    float pp[4][4], hh[4][4], Cv[4][4];
    float P4[4], H4[4];
    #pragma unroll
    for (int rt = 0; rt < 4; ++rt) {
        float p = 1.0f, h = 0.0f;
        #pragma unroll
        for (int r = 0; r < 4; ++r) {
            float xp = acc[rt][0][r] + bxv;
            float bm = acc[rt][1][r] + bbv;
            float cc = acc[rt][2][r] + bcv;
            float dd = acc[rt][3][r] + bdv;
            dd = fminf(dd, 60.0f);
            float e  = __expf(dd);
            float A  = 1.0f / (1.0f + e);        // exp(-softplus(d))
            float u  = (e * A) * bm * xp;        // (1-A)*Bm*x_proj
            h = fmaf(A, h, u);
            p *= A;
            pp[rt][r] = p;
            hh[rt][r] = h;
            Cv[rt][r] = cc;
        }
        P4[rt] = p;
        H4[rt] = h;
    }

    // step 2: cross-lq scan per rt (runs ordered by lq = ascending t)
    float eP[4], eH[4], TP[4], TH[4];
    #pragma unroll
    for (int rt = 0; rt < 4; ++rt) {
        float iP = P4[rt], iH = H4[rt];
        float tP = __shfl_up(iP, 16, 64);
        float tH = __shfl_up(iH, 16, 64);
        if (lq >= 1) { iH = fmaf(iP, tH, iH); iP *= tP; }
        tP = __shfl_up(iP, 32, 64);
        tH = __shfl_up(iH, 32, 64);
        if (lq >= 2) { iH = fmaf(iP, tH, iH); iP *= tP; }
        // exclusive carry into this run
        float xP = __shfl_up(iP, 16, 64);
        float xH = __shfl_up(iH, 16, 64);
        eP[rt] = (lq >= 1) ? xP : 1.0f;
        eH[rt] = (lq >= 1) ? xH : 0.0f;
        // block16 total: broadcast from lane (lq=3, same lm)
        TP[rt] = __shfl(iP, 48 + lm, 64);
        TH[rt] = __shfl(iH, 48 + lm, 64);
    }

    // barrier BEFORE overlay writes (GEMM-phase LDS reads must be done)
    __syncthreads();

    // step 3: cross-rt compose + final per-element pack into LDS
    {
        float bP = 1.0f, bH = 0.0f;    // exclusive carry into block16 rt
        #pragma unroll
        for (int rt = 0; rt < 4; ++rt) {
            // carry into run (rt, lq): compose(E16, Erun)
            float cP = bP * eP[rt];
            float cH = fmaf(eP[rt], bH, eH[rt]);
            #pragma unroll
            for (int r = 0; r < 4; ++r) {
                float Pf = cP * pp[rt][r];               // Apre(t)
                float Hf = fmaf(pp[rt][r], cH, hh[rt][r]); // hloc(t)
                uint_t g1 = f2bf(Cv[rt][r] * Hf);
                uint_t g2 = f2bf(Cv[rt][r] * Pf);
                const int t = rt * 16 + lq * 4 + r;
                sh.s.po[t][jn] = (g2 << 16) | g1;
            }
            // advance E16 by block total
            bH = fmaf(TP[rt], bH, TH[rt]);
            bP *= TP[rt];
        }
        // chunk summary (same value on all lanes; lq==0 lanes write)
        if (lq == 0) {
            const size_t sidx = (size_t)blockIdx.x * NST + ng;
            Aprod[sidx] = bP;
            Hend [sidx] = bH;
        }
    }
    __syncthreads();

    // coalesced HP store: 64 B contiguous per thread
    {
        const int r  = tid >> 2;
        const int nq = (tid & 3) * 16;
        const uint_t* src = &sh.s.po[r][0] + nq;
        uint_t* dst = HP + (size_t)(row0 + r) * NST + n0 + nq;
        uint4 v0 = *(const uint4*)(src);
        uint4 v1 = *(const uint4*)(src + 4);
        uint4 v2 = *(const uint4*)(src + 8);
        uint4 v3 = *(const uint4*)(src + 12);
        *(uint4*)(dst)      = v0;
        *(uint4*)(dst + 4)  = v1;
        *(uint4*)(dst + 8)  = v2;
        *(uint4*)(dst + 12) = v3;
    }
}

// ---------------------------------------------------------------------------
// carry: per (b, n) sequential scan over the 64 chunk summaries.
// Carry[b, c, n] = h entering chunk c.
// ---------------------------------------------------------------------------
__global__ __launch_bounds__(256)
void scan_carry_kernel(const float* __restrict__ Aprod, const float* __restrict__ Hend,
                       float* __restrict__ Carry)
{
    const int gid = blockIdx.x * 256 + threadIdx.x;   // 0 .. BB*NST-1
    const int n   = gid & (NST - 1);
    const int b   = gid >> 9;
    float h = 0.0f;
    for (int c = 0; c < NC; ++c) {
        size_t idx = ((size_t)(b * NC + c)) * NST + n;
        Carry[idx] = h;
        h = fmaf(Aprod[idx], h, Hend[idx]);
    }
}

// ---------------------------------------------------------------------------
// out_fused: out = y @ Wy + by where y(t,n) = G1 + G2*carry(chunk,n) is
// reconstructed from packed HP during LDS staging. Tile 64 rows x 64 cols.
// Row block == one chunk, so carry row is block-uniform.
// ---------------------------------------------------------------------------
__global__ __launch_bounds__(256, 4)
void out_fused_kernel(const uint_t* __restrict__ HP, const float* __restrict__ Carry,
                      const ushort_t* __restrict__ Wyt, const float* __restrict__ by,
                      float* __restrict__ out)
{
    __shared__ alignas(16) ushort_t ys [64][72];
    __shared__ alignas(16) ushort_t wys[64][72];

    const int tid  = threadIdx.x;
    const int wave = tid >> 6;
    const int lane = tid & 63;
    const int lm   = lane & 15;
    const int lq   = lane >> 4;
    const int row0 = blockIdx.x * 64;     // == chunk * LC
    const int n0   = blockIdx.y * 64;

    const int sr = tid >> 2;
    const int sk = (tid & 3) << 4;

    f32x4 acc[4];
    #pragma unroll
    for (int rt = 0; rt < 4; ++rt) acc[rt] = (f32x4){0.f, 0.f, 0.f, 0.f};

    const uint_t*   hsrc = HP  + (size_t)(row0 + sr) * NST + sk;
    const ushort_t* wsrc = Wyt + (size_t)(n0  + sr) * NST + sk;
    const float*    carr = Carry + (size_t)blockIdx.x * NST + sk;

    for (int k0 = 0; k0 < NST; k0 += 64) {
        uint4 hv[4];
        #pragma unroll
        for (int q = 0; q < 4; ++q) hv[q] = *(const uint4*)(hsrc + k0 + q * 4);
        float4 cv[4];
        #pragma unroll
        for (int q = 0; q < 4; ++q) cv[q] = *(const float4*)(carr + k0 + q * 4);
        uint4 wv0 = *(const uint4*)(wsrc + k0);
        uint4 wv1 = *(const uint4*)(wsrc + k0 + 8);

        // y = G1 + G2*carry -> bf16, pack 16 elems
        uint_t yo[8];
        #pragma unroll
        for (int q = 0; q < 4; ++q) {
            const float* cvp = (const float*)&cv[q];
            const uint_t* hvp = (const uint_t*)&hv[q];
            #pragma unroll
            for (int e = 0; e < 4; e += 2) {
                uint_t pk0 = hvp[e], pk1 = hvp[e + 1];
                float y0 = fmaf(bf2f((ushort_t)(pk0 >> 16)), cvp[e],
                                bf2f((ushort_t)(pk0 & 0xffff)));
                float y1 = fmaf(bf2f((ushort_t)(pk1 >> 16)), cvp[e + 1],
                                bf2f((ushort_t)(pk1 & 0xffff)));
                yo[q * 2 + e / 2] = (uint_t)f2bf(y0) | ((uint_t)f2bf(y1) << 16);
            }
        }
        __syncthreads();
        *(uint4*)&ys[sr][sk]      = *(uint4*)&yo[0];
        *(uint4*)&ys[sr][sk + 8]  = *(uint4*)&yo[4];
        *(uint4*)&wys[sr][sk]     = wv0;
        *(uint4*)&wys[sr][sk + 8] = wv1;
        __syncthreads();

        #pragma unroll
        for (int ks = 0; ks < 2; ++ks) {
            const int kk = ks * 32 + lq * 8;
            bf16x8 bfr = *(const bf16x8*)&wys[wave * 16 + lm][kk];
            #pragma unroll
            for (int rt = 0; rt < 4; ++rt) {
                bf16x8 af = *(const bf16x8*)&ys[rt * 16 + lm][kk];
                acc[rt] = __builtin_amdgcn_mfma_f32_16x16x32_bf16(
                    af, bfr, acc[rt], 0, 0, 0);
            }
        }
    }

    const int ng = n0 + wave * 16 + lm;
    const float bv = by[ng];
    #pragma unroll
    for (int rt = 0; rt < 4; ++rt)
        #pragma unroll
        for (int r = 0; r < 4; ++r) {
            const int row = row0 + rt * 16 + lq * 4 + r;
            out[(size_t)row * COUT + ng] = acc[rt][r] + bv;
        }
}

// ---------------------------------------------------------------------------
// Workspace layout (bytes, 16B aligned):
//   HP    uint32 ROWS*NST    33,554,432   (packed bf16 G2|G1)
//   xb    bf16   ROWS*CIN     8,388,608
//   Wt    bf16   4*NST*CIN    1,048,576
//   Wyt   bf16   COUT*NST       262,144
//   Aprod fp32   BB*NC*NST      524,288
//   Hend  fp32   BB*NC*NST      524,288
//   Carry fp32   BB*NC*NST      524,288
// total 44,826,624 B
// ---------------------------------------------------------------------------
extern "C" void kernel_launch(void* const* d_in, const int* in_sizes, int n_in,
                              void* d_out, int out_size, void* d_ws, size_t ws_size,
                              hipStream_t stream)
{
    const float* x   = (const float*)d_in[0];
    const float* Wx  = (const float*)d_in[1];
    const float* bx  = (const float*)d_in[2];
    const float* Wbc = (const float*)d_in[3];
    const float* bbc = (const float*)d_in[4];
    const float* Wd  = (const float*)d_in[5];
    const float* bd  = (const float*)d_in[6];
    const float* Wy  = (const float*)d_in[7];
    const float* by  = (const float*)d_in[8];
    float* out = (float*)d_out;

    char* p = (char*)d_ws;
    uint_t*   HP    = (uint_t*)p;         p += (size_t)ROWS * NST * 4;
    ushort_t* xb    = (ushort_t*)p;       p += (size_t)ROWS * CIN * 2;
    ushort_t* Wt    = (ushort_t*)p;       p += (size_t)4 * NST * CIN * 2;
    ushort_t* Wyt   = (ushort_t*)p;       p += (size_t)COUT * NST * 2;
    float*    Aprod = (float*)p;          p += (size_t)BB * NC * NST * 4;
    float*    Hend  = (float*)p;          p += (size_t)BB * NC * NST * 4;
    float*    Carry = (float*)p;          p += (size_t)BB * NC * NST * 4;

    const int prep_threads = ROWS * CIN / 4 + 4 * NST * CIN + COUT * NST;
    prep_kernel<<<prep_threads / 256, 256, 0, stream>>>(
        x, Wx, Wbc, Wd, Wy, xb, Wt, Wyt);

    proj_mfma_scan_kernel<<<dim3(ROWS / 64, NST / 64), 256, 0, stream>>>(
        xb, Wt, bx, bbc, bd, HP, Aprod, Hend);

    scan_carry_kernel<<<(BB * NST) / 256, 256, 0, stream>>>(
        Aprod, Hend, Carry);

    out_fused_kernel<<<dim3(ROWS / 64, COUT / 64), 256, 0, stream>>>(
        HP, Carry, Wyt, by, out);
}